// Round 14
// baseline (51.215 us; speedup 1.0000x reference)
//
#include <hip/hip_runtime.h>
#include <math.h>

#define GRID     64
#define NCELLS   (GRID * GRID)        // 4096 cells, 8x8 px each
#define INV_CELL 0.125f
#define CELLSZ   8.0f

__device__ __forceinline__ int clampi(int v, int lo, int hi) {
    return v < lo ? lo : (v > hi ? hi : v);
}
__device__ __forceinline__ int cell_of(float x, float y) {
    const int cx = clampi((int)(x * INV_CELL), 0, GRID - 1);
    const int cy = clampi((int)(y * INV_CELL), 0, GRID - 1);
    return cy * GRID + cx;
}

// K1 (ONE block): zero + histogram + scan + scatter, all via LDS.
// Bin order within a cell is atomic-order-dependent; the downstream min
// over each cell is order-invariant, so the final result is deterministic.
__global__ __launch_bounds__(256) void chamfer_setup(
    const float2* __restrict__ p, int np,
    const float2* __restrict__ q, int nq,
    int* __restrict__ startP, int* __restrict__ startQ,
    float2* __restrict__ binP, float2* __restrict__ binQ,
    float* __restrict__ out)
{
    __shared__ int hP[NCELLS];
    __shared__ int hQ[NCELLS];
    __shared__ int ls[256];
    const int t = threadIdx.x;
    if (t == 0) out[0] = 0.f;
    for (int k = t; k < NCELLS; k += 256) { hP[k] = 0; hQ[k] = 0; }
    __syncthreads();

    // ---- histogram (float4 = 2 points per load, 4 loads per iteration) ----
    const float4* __restrict__ p4 = (const float4*)p;
    const float4* __restrict__ q4 = (const float4*)q;
    const int np2 = np >> 1, nq2 = nq >> 1;   // N,M are even (16384)
    for (int i = t; i < np2; i += 256) {
        float4 v = p4[i];
        atomicAdd(&hP[cell_of(v.x, v.y)], 1);
        atomicAdd(&hP[cell_of(v.z, v.w)], 1);
    }
    for (int i = t; i < nq2; i += 256) {
        float4 v = q4[i];
        atomicAdd(&hQ[cell_of(v.x, v.y)], 1);
        atomicAdd(&hQ[cell_of(v.z, v.w)], 1);
    }
    __syncthreads();

    // ---- exclusive scan P (16 cells/thread + 256-wide LDS scan) ----
    {
        const int base = t * 16;
        int loc[16], s = 0;
        #pragma unroll
        for (int k = 0; k < 16; ++k) { loc[k] = hP[base + k]; s += loc[k]; }
        ls[t] = s; __syncthreads();
        for (int off = 1; off < 256; off <<= 1) {
            int v = (t >= off) ? ls[t - off] : 0;
            __syncthreads();
            ls[t] += v;
            __syncthreads();
        }
        int ex = ls[t] - s;
        #pragma unroll
        for (int k = 0; k < 16; ++k) {
            startP[base + k] = ex; hP[base + k] = ex; ex += loc[k];
        }
        if (t == 0) startP[NCELLS] = np;
    }
    __syncthreads();
    // ---- exclusive scan Q ----
    {
        const int base = t * 16;
        int loc[16], s = 0;
        #pragma unroll
        for (int k = 0; k < 16; ++k) { loc[k] = hQ[base + k]; s += loc[k]; }
        ls[t] = s; __syncthreads();
        for (int off = 1; off < 256; off <<= 1) {
            int v = (t >= off) ? ls[t - off] : 0;
            __syncthreads();
            ls[t] += v;
            __syncthreads();
        }
        int ex = ls[t] - s;
        #pragma unroll
        for (int k = 0; k < 16; ++k) {
            startQ[base + k] = ex; hQ[base + k] = ex; ex += loc[k];
        }
        if (t == 0) startQ[NCELLS] = nq;
    }
    __syncthreads();

    // ---- scatter via LDS cursors ----
    for (int i = t; i < np2; i += 256) {
        float4 v = p4[i];
        binP[atomicAdd(&hP[cell_of(v.x, v.y)], 1)] = make_float2(v.x, v.y);
        binP[atomicAdd(&hP[cell_of(v.z, v.w)], 1)] = make_float2(v.z, v.w);
    }
    for (int i = t; i < nq2; i += 256) {
        float4 v = q4[i];
        binQ[atomicAdd(&hQ[cell_of(v.x, v.y)], 1)] = make_float2(v.x, v.y);
        binQ[atomicAdd(&hQ[cell_of(v.z, v.w)], 1)] = make_float2(v.z, v.w);
    }
}

__device__ __forceinline__ float scan_range(
    const float2* __restrict__ tb, int s, int e,
    float qx, float qy, float best)
{
    for (int k = s; k < e; ++k) {
        float2 v = tb[k];
        float dx = qx - v.x, dy = qy - v.y;
        best = fminf(best, fmaf(dx, dx, dy * dy));
    }
    return best;
}

// K2: exact NN. Fast path: the 3x3 neighborhood = 3 CONTIGUOUS point ranges
// (cells in a row are adjacent in the binned array). After cheb ring r, any
// unscanned cell is > r*8 px away  =>  stop when best <= (8r)^2.
// 128-thr blocks -> 256 blocks = 1 per CU (latency-bound; max CU coverage).
__global__ __launch_bounds__(128) void chamfer_search(
    const float2* __restrict__ binP, int np,
    const float2* __restrict__ binQ, int nq,
    const int* __restrict__ startP, const int* __restrict__ startQ,
    float* __restrict__ out)
{
    const int i = blockIdx.x * 128 + threadIdx.x;
    const int total = np + nq;
    float d = 0.f;
    if (i < total) {
        const bool sideP = (i < np);
        const float2 qry = sideP ? binP[i] : binQ[i - np];
        const float2* __restrict__ tb = sideP ? binQ : binP;
        const int*    __restrict__ ts = sideP ? startQ : startP;
        const int cx = clampi((int)(qry.x * INV_CELL), 0, GRID - 1);
        const int cy = clampi((int)(qry.y * INV_CELL), 0, GRID - 1);
        float best = 3.0e38f;

        // fused 3x3 (rings 0+1): 3 contiguous ranges
        const int x0 = max(cx - 1, 0), x1 = min(cx + 1, GRID - 1);
        const int y0 = max(cy - 1, 0), y1 = min(cy + 1, GRID - 1);
        for (int y = y0; y <= y1; ++y) {
            const int rb = y * GRID;
            best = scan_range(tb, ts[rb + x0], ts[rb + x1 + 1],
                              qry.x, qry.y, best);
        }

        if (best > CELLSZ * CELLSZ) {       // rare: expand rings from r=2
            for (int r = 2; r < GRID; ++r) {
                const int xa = max(cx - r, 0), xb = min(cx + r, GRID - 1);
                const int yT = cy - r, yB = cy + r;
                if (yT >= 0)
                    best = scan_range(tb, ts[yT * GRID + xa],
                                      ts[yT * GRID + xb + 1], qry.x, qry.y, best);
                if (yB < GRID)
                    best = scan_range(tb, ts[yB * GRID + xa],
                                      ts[yB * GRID + xb + 1], qry.x, qry.y, best);
                const int ya = max(cy - r + 1, 0), yb = min(cy + r - 1, GRID - 1);
                for (int y = ya; y <= yb; ++y) {
                    if (cx - r >= 0) {
                        const int c = y * GRID + cx - r;
                        best = scan_range(tb, ts[c], ts[c + 1], qry.x, qry.y, best);
                    }
                    if (cx + r < GRID) {
                        const int c = y * GRID + cx + r;
                        best = scan_range(tb, ts[c], ts[c + 1], qry.x, qry.y, best);
                    }
                }
                const float bnd = (float)r * CELLSZ;
                if (best <= bnd * bnd) break;
            }
        }
        d = sqrtf(fmaxf(best, 0.f));
    }

    #pragma unroll
    for (int off = 32; off > 0; off >>= 1) d += __shfl_down(d, off);
    __shared__ float s[2];
    if ((threadIdx.x & 63) == 0) s[threadIdx.x >> 6] = d;
    __syncthreads();
    if (threadIdx.x == 0) atomicAdd(out, s[0] + s[1]);
}

extern "C" void kernel_launch(void* const* d_in, const int* in_sizes, int n_in,
                              void* d_out, int out_size, void* d_ws, size_t ws_size,
                              hipStream_t stream) {
    const float2* p = (const float2*)d_in[0];   // (16384, 2) f32
    const float2* q = (const float2*)d_in[1];   // (16384, 2) f32
    const int N = in_sizes[0] / 2;
    const int M = in_sizes[1] / 2;
    float* out = (float*)d_out;

    // ws layout
    int* startP  = (int*)d_ws;                  // NCELLS+1
    int* startQ  = startP + NCELLS + 1;         // NCELLS+1
    float2* binP = (float2*)(startQ + NCELLS + 1);  // N entries (8B aligned)
    float2* binQ = binP + N;                    // M entries

    hipLaunchKernelGGL(chamfer_setup, dim3(1), dim3(256), 0, stream,
                       p, N, q, M, startP, startQ, binP, binQ, out);

    const int nbS = (N + M + 127) / 128;
    hipLaunchKernelGGL(chamfer_search, dim3(nbS), dim3(128), 0, stream,
                       binP, N, binQ, M, startP, startQ, out);
}

// Round 15
// 28.384 us; speedup vs baseline: 1.8044x; 1.8044x over previous
//
#include <hip/hip_runtime.h>
#include <math.h>

#define GRID     64
#define NCELLS   (GRID * GRID)        // 4096 cells, 8x8 px each
#define INV_CELL 0.125f
#define CELLSZ   8.0f

__device__ __forceinline__ int clampi(int v, int lo, int hi) {
    return v < lo ? lo : (v > hi ? hi : v);
}
__device__ __forceinline__ int cell_of(float x, float y) {
    const int cx = clampi((int)(x * INV_CELL), 0, GRID - 1);
    const int cy = clampi((int)(y * INV_CELL), 0, GRID - 1);
    return cy * GRID + cx;
}

// K1 (2 blocks, one per set): LDS-zero + histogram + scan, fused.
// Each block streams only its own 128 KB point set; histogram lives in LDS
// (per-launch, so no global zeroing kernel); exclusive scan in LDS; writes
// start[] (search) and cur[] (scatter cursors) to global.
__global__ __launch_bounds__(256) void chamfer_setup2(
    const float2* __restrict__ p, int np,
    const float2* __restrict__ q, int nq,
    int* __restrict__ startP, int* __restrict__ startQ,
    int* __restrict__ curP, int* __restrict__ curQ,
    float* __restrict__ out)
{
    const int side = blockIdx.x;           // 0 -> P, 1 -> Q
    const float2* __restrict__ pts = side ? q : p;
    const int n = side ? nq : np;
    int* __restrict__ start = side ? startQ : startP;
    int* __restrict__ cur   = side ? curQ : curP;

    __shared__ int hist[NCELLS];
    __shared__ int ls[256];
    const int t = threadIdx.x;
    if (side == 0 && t == 0) out[0] = 0.f;
    for (int k = t; k < NCELLS; k += 256) hist[k] = 0;
    __syncthreads();

    // histogram: float4 = 2 points per load
    const float4* __restrict__ pts4 = (const float4*)pts;
    const int n2 = n >> 1;                 // n is even (16384)
    for (int i = t; i < n2; i += 256) {
        float4 v = pts4[i];
        atomicAdd(&hist[cell_of(v.x, v.y)], 1);
        atomicAdd(&hist[cell_of(v.z, v.w)], 1);
    }
    __syncthreads();

    // exclusive scan: 16 cells/thread + 256-wide LDS scan
    const int base = t * 16;
    int loc[16], s = 0;
    #pragma unroll
    for (int k = 0; k < 16; ++k) { loc[k] = hist[base + k]; s += loc[k]; }
    ls[t] = s; __syncthreads();
    for (int off = 1; off < 256; off <<= 1) {
        int v = (t >= off) ? ls[t - off] : 0;
        __syncthreads();
        ls[t] += v;
        __syncthreads();
    }
    int ex = ls[t] - s;
    #pragma unroll
    for (int k = 0; k < 16; ++k) {
        start[base + k] = ex; cur[base + k] = ex; ex += loc[k];
    }
    if (t == 0) start[NCELLS] = n;
}

// K2: scatter points into cell-sorted arrays (bin order within a cell is
// atomic-order-dependent; downstream min is order-invariant -> deterministic)
__global__ __launch_bounds__(256) void chamfer_scatter(
    const float2* __restrict__ p, int np,
    const float2* __restrict__ q, int nq,
    int* __restrict__ curP, int* __restrict__ curQ,
    float2* __restrict__ binP, float2* __restrict__ binQ)
{
    const int i = blockIdx.x * 256 + threadIdx.x;
    if (i < np) { float2 v = p[i];
                  binP[atomicAdd(&curP[cell_of(v.x, v.y)], 1)] = v; }
    if (i < nq) { float2 v = q[i];
                  binQ[atomicAdd(&curQ[cell_of(v.x, v.y)], 1)] = v; }
}

__device__ __forceinline__ float scan_range(
    const float2* __restrict__ tb, int s, int e,
    float qx, float qy, float best)
{
    for (int k = s; k < e; ++k) {
        float2 v = tb[k];
        float dx = qx - v.x, dy = qy - v.y;
        best = fminf(best, fmaf(dx, dx, dy * dy));
    }
    return best;
}

// K3: exact NN. 3x3 neighborhood = 3 CONTIGUOUS ranges; all 6 range-index
// loads issued up front (independent) -> one L2 round-trip on the chain.
// After cheb ring r, any unscanned cell is > r*8 px  =>  stop when
// best <= (8r)^2. 128-thr blocks -> 256 blocks = 1 per CU.
__global__ __launch_bounds__(128) void chamfer_search(
    const float2* __restrict__ binP, int np,
    const float2* __restrict__ binQ, int nq,
    const int* __restrict__ startP, const int* __restrict__ startQ,
    float* __restrict__ out)
{
    const int i = blockIdx.x * 128 + threadIdx.x;
    const int total = np + nq;
    float d = 0.f;
    if (i < total) {
        const bool sideP = (i < np);
        const float2 qry = sideP ? binP[i] : binQ[i - np];
        const float2* __restrict__ tb = sideP ? binQ : binP;
        const int*    __restrict__ ts = sideP ? startQ : startP;
        const int cx = clampi((int)(qry.x * INV_CELL), 0, GRID - 1);
        const int cy = clampi((int)(qry.y * INV_CELL), 0, GRID - 1);
        float best = 3.0e38f;

        // fused 3x3 (rings 0+1): issue all index loads first
        const int x0 = max(cx - 1, 0), x1 = min(cx + 1, GRID - 1);
        const int y0 = max(cy - 1, 0), y1 = min(cy + 1, GRID - 1);
        int sA[3], eA[3];
        #pragma unroll
        for (int k = 0; k < 3; ++k) {
            const int y = min(y0 + k, y1);        // clamp duplicates row (harmless)
            sA[k] = ts[y * GRID + x0];
            eA[k] = ts[y * GRID + x1 + 1];
        }
        const int ny = y1 - y0 + 1;
        for (int k = 0; k < ny; ++k)
            best = scan_range(tb, sA[k], eA[k], qry.x, qry.y, best);

        if (best > CELLSZ * CELLSZ) {       // rare: expand rings from r=2
            for (int r = 2; r < GRID; ++r) {
                const int xa = max(cx - r, 0), xb = min(cx + r, GRID - 1);
                const int yT = cy - r, yB = cy + r;
                if (yT >= 0)
                    best = scan_range(tb, ts[yT * GRID + xa],
                                      ts[yT * GRID + xb + 1], qry.x, qry.y, best);
                if (yB < GRID)
                    best = scan_range(tb, ts[yB * GRID + xa],
                                      ts[yB * GRID + xb + 1], qry.x, qry.y, best);
                const int ya = max(cy - r + 1, 0), yb = min(cy + r - 1, GRID - 1);
                for (int y = ya; y <= yb; ++y) {
                    if (cx - r >= 0) {
                        const int c = y * GRID + cx - r;
                        best = scan_range(tb, ts[c], ts[c + 1], qry.x, qry.y, best);
                    }
                    if (cx + r < GRID) {
                        const int c = y * GRID + cx + r;
                        best = scan_range(tb, ts[c], ts[c + 1], qry.x, qry.y, best);
                    }
                }
                const float bnd = (float)r * CELLSZ;
                if (best <= bnd * bnd) break;
            }
        }
        d = sqrtf(fmaxf(best, 0.f));
    }

    #pragma unroll
    for (int off = 32; off > 0; off >>= 1) d += __shfl_down(d, off);
    __shared__ float s[2];
    if ((threadIdx.x & 63) == 0) s[threadIdx.x >> 6] = d;
    __syncthreads();
    if (threadIdx.x == 0) atomicAdd(out, s[0] + s[1]);
}

extern "C" void kernel_launch(void* const* d_in, const int* in_sizes, int n_in,
                              void* d_out, int out_size, void* d_ws, size_t ws_size,
                              hipStream_t stream) {
    const float2* p = (const float2*)d_in[0];   // (16384, 2) f32
    const float2* q = (const float2*)d_in[1];   // (16384, 2) f32
    const int N = in_sizes[0] / 2;
    const int M = in_sizes[1] / 2;
    float* out = (float*)d_out;

    // ws layout
    int* startP  = (int*)d_ws;                      // NCELLS+1
    int* startQ  = startP + NCELLS + 1;             // NCELLS+1
    int* curP    = startQ + NCELLS + 1;             // NCELLS
    int* curQ    = curP + NCELLS;                   // NCELLS
    float2* binP = (float2*)(curQ + NCELLS + 2);    // N entries (8B aligned)
    float2* binQ = binP + N;                        // M entries

    hipLaunchKernelGGL(chamfer_setup2, dim3(2), dim3(256), 0, stream,
                       p, N, q, M, startP, startQ, curP, curQ, out);

    const int nbPQ = (max(N, M) + 255) / 256;
    hipLaunchKernelGGL(chamfer_scatter, dim3(nbPQ), dim3(256), 0, stream,
                       p, N, q, M, curP, curQ, binP, binQ);

    const int nbS = (N + M + 127) / 128;
    hipLaunchKernelGGL(chamfer_search, dim3(nbS), dim3(128), 0, stream,
                       binP, N, binQ, M, startP, startQ, out);
}